// Round 13
// baseline (141.775 us; speedup 1.0000x reference)
//
#include <hip/hip_runtime.h>
#include <hip/hip_bf16.h>
#include <math.h>

typedef __bf16 bf16;
typedef __attribute__((ext_vector_type(8))) __bf16 bf16x8;
typedef __attribute__((ext_vector_type(4))) __bf16 bf16x4;
typedef __attribute__((ext_vector_type(4))) float f32x4;

#define MFMA16(a, b, c) __builtin_amdgcn_mfma_f32_16x16x32_bf16((a), (b), (c), 0, 0, 0)

// Problem dims
// B=32, T=1024, VOCAB=512, RANK=256
// x [32768, 512] f32 ; W_attn [512,768] ; b_attn[768] ; W_proj [256,512] ; b_proj[512]

// ---------------- weight convert+transpose (tiny) ----------------
__global__ __launch_bounds__(256) void cvt_wattn(const float* __restrict__ w,
                                                 bf16* __restrict__ wt) {
  int o = blockIdx.x * 256 + threadIdx.x;   // 768*512 = 393216
  int n = o >> 9, kk = o & 511;
  wt[o] = (bf16)w[kk * 768 + n];            // WT[n][k] = W[k][n]
}

__global__ __launch_bounds__(256) void cvt_wproj(const float* __restrict__ w,
                                                 bf16* __restrict__ wt) {
  int o = blockIdx.x * 256 + threadIdx.x;   // 512*256 = 131072
  int n = o >> 8, kk = o & 255;
  wt[o] = (bf16)w[kk * 512 + n];            // WT[n][k] = W[k][n]
}

// ---------------- qkv GEMM: [32768,512]f32 x [768,512]^T ----------------
// v13: 256x128 tile, 512 threads / 8 waves -> 768 blocks (3 slots/CU):
// halves per-CU barrier-chain count at CONSTANT per-wave VGPR (r11's lesson).
// 2-barrier BK=32 step (r10's proven best), T14 reg-prefetch, swapped MFMA,
// fused transposed-v store, XCD-chunked grid.
__global__ __launch_bounds__(512) void gemm_qkv(
    const float* __restrict__ x, const bf16* __restrict__ WT,
    const float* __restrict__ b_attn,
    bf16* __restrict__ qo, bf16* __restrict__ ko, bf16* __restrict__ vto) {
  __shared__ __attribute__((aligned(16))) bf16 As[256][40];
  __shared__ __attribute__((aligned(16))) bf16 Bs[128][40];
  const int tid = threadIdx.x;
  // 768 blocks: xcd = id&7 owns 96 = 16 M-panels x 6 N-blocks (N fastest)
  const int id = blockIdx.x;
  const int xcd = id & 7;
  const int rest = id >> 3;          // 0..95
  const int bmL = rest / 6;          // 0..15
  const int bn = (rest % 6) * 128;
  const int bm = (xcd * 16 + bmL) * 256;
  const int lane = tid & 63, wid = tid >> 6;     // 8 waves
  const int l15 = lane & 15, lg = lane >> 4;
  const int wm = (wid >> 1) * 64;    // 0,64,128,192
  const int wn = (wid & 1) * 64;     // 0,64

  f32x4 acc[4][4] = {};

  // A staging: 256 rows x 32 cols f32->bf16; thread -> row tid>>1, col (tid&1)*16
  const int sra = tid >> 1;
  const int sca = (tid & 1) * 16;
  // B staging: 128 rows x 32 cols bf16; thread -> row tid>>2, col (tid&3)*8
  const int srb = tid >> 2;
  const int scb = (tid & 3) * 8;
  const float* xp = x + (size_t)(bm + sra) * 512 + sca;
  const bf16* wp = WT + (size_t)(bn + srb) * 512 + scb;

  // T14 prologue: load + convert K-step 0 into regs
  bf16x8 ha[2], hb;
  {
    f32x4 f0 = *(const f32x4*)(xp);
    f32x4 f1 = *(const f32x4*)(xp + 4);
    f32x4 f2 = *(const f32x4*)(xp + 8);
    f32x4 f3 = *(const f32x4*)(xp + 12);
#pragma unroll
    for (int e = 0; e < 4; ++e) {
      ha[0][e] = (bf16)f0[e]; ha[0][e + 4] = (bf16)f1[e];
      ha[1][e] = (bf16)f2[e]; ha[1][e + 4] = (bf16)f3[e];
    }
    hb = *(const bf16x8*)(wp);
  }

  for (int kt = 0; kt < 16; ++kt) {
    __syncthreads();   // previous step's LDS reads done
    *(bf16x8*)&As[sra][sca] = ha[0];
    *(bf16x8*)&As[sra][sca + 8] = ha[1];
    *(bf16x8*)&Bs[srb][scb] = hb;
    __syncthreads();
    if (kt < 15) {     // prefetch next K-step; drains under the MFMAs below
      const float* xq = xp + (kt + 1) * 32;
      f32x4 f0 = *(const f32x4*)(xq);
      f32x4 f1 = *(const f32x4*)(xq + 4);
      f32x4 f2 = *(const f32x4*)(xq + 8);
      f32x4 f3 = *(const f32x4*)(xq + 12);
#pragma unroll
      for (int e = 0; e < 4; ++e) {
        ha[0][e] = (bf16)f0[e]; ha[0][e + 4] = (bf16)f1[e];
        ha[1][e] = (bf16)f2[e]; ha[1][e + 4] = (bf16)f3[e];
      }
      hb = *(const bf16x8*)(wp + (kt + 1) * 32);
    }
    bf16x8 af[4], bfr[4];
#pragma unroll
    for (int mi = 0; mi < 4; ++mi)
      af[mi] = *(const bf16x8*)&As[wm + mi * 16 + l15][lg * 8];
#pragma unroll
    for (int ni = 0; ni < 4; ++ni)
      bfr[ni] = *(const bf16x8*)&Bs[wn + ni * 16 + l15][lg * 8];
    // swapped: A = W (N side in regs), B = x (M side on lanes)
    __builtin_amdgcn_s_setprio(1);
#pragma unroll
    for (int mi = 0; mi < 4; ++mi)
#pragma unroll
      for (int ni = 0; ni < 4; ++ni)
        acc[mi][ni] = MFMA16(bfr[ni], af[mi], acc[mi][ni]);
    __builtin_amdgcn_s_setprio(0);
  }

  // epilogue: row = bm+wm+mi*16+l15 (lane), cols = bn+wn+ni*16+lg*4+r (regs)
  // seg 0=q 1=k -> row-major [t][d]; 2=v -> transposed store to vt[b][d][t]
#pragma unroll
  for (int ni = 0; ni < 4; ++ni) {
    int gc0 = bn + wn + ni * 16 + lg * 4;
    f32x4 bias = *(const f32x4*)(b_attn + gc0);
    int seg = gc0 >> 8;
    int cc = gc0 & 255;
    if (seg == 2) {
#pragma unroll
      for (int mi = 0; mi < 4; ++mi) {
        int gr = bm + wm + mi * 16 + l15;
        bf16* vp = vto + (size_t)(gr >> 10) * 262144 + (size_t)cc * 1024 + (gr & 1023);
#pragma unroll
        for (int r = 0; r < 4; ++r)
          vp[(size_t)r * 1024] = (bf16)(acc[mi][ni][r] + bias[r]);
      }
    } else {
      bf16* op = (seg == 0) ? qo : ko;
#pragma unroll
      for (int mi = 0; mi < 4; ++mi) {
        int gr = bm + wm + mi * 16 + l15;
        bf16x4 pk;
#pragma unroll
        for (int r = 0; r < 4; ++r) pk[r] = (bf16)(acc[mi][ni][r] + bias[r]);
        *(bf16x4*)(op + (size_t)gr * 256 + cc) = pk;
      }
    }
  }
}

// ---------------- flash attention, causal, scale 1/16 (r10, keep) ----------------
__global__ __launch_bounds__(256) void attn_fwd(
    const bf16* __restrict__ q, const bf16* __restrict__ k,
    const bf16* __restrict__ vt, bf16* __restrict__ y) {
  __shared__ __attribute__((aligned(16))) bf16 Ks[64 * 256];    // 32KB, 512B rows, swz
  __shared__ __attribute__((aligned(16))) bf16 Vt[256 * 64];    // 32KB, 128B rows, swz
  __shared__ __attribute__((aligned(16))) bf16 Ps[4 * 16 * 64]; // 8KB per-wave P, swz
  const int tid = threadIdx.x, lane = tid & 63, wid = tid >> 6;
  const int l15 = lane & 15, lg = lane >> 4;

  // 512 blocks: id = xcd + 8*u, u = bg + 4*j (j=0..15); batch = xcd + 8*bg
  const int id = blockIdx.x;
  const int xcd = id & 7, u = id >> 3;
  const int bg = u & 3, j = u >> 2;
  const int b = xcd + 8 * bg;
  const int qt = (j < 8) ? j : 23 - j;   // u and u+32 -> qt and 15-qt
  const int q0 = qt * 64 + wid * 16;

  bf16x8 qf[8];
  {
    const bf16* qp = q + (size_t)(b * 1024 + q0 + l15) * 256 + lg * 8;
#pragma unroll
    for (int d = 0; d < 8; ++d) qf[d] = *(const bf16x8*)(qp + d * 32);
  }
  f32x4 o[16] = {};     // o[df][r]: d = df*16 + lg*4 + r, q = q0 + l15
  float m_st = -1e30f;  // running max for q = q0+l15
  float l_st = 0.f;     // running denom

  const char* kbase = (const char*)(k + (size_t)b * 262144);
  const char* vtbase = (const char*)(vt + (size_t)b * 262144);
  const int ksr = tid >> 5;            // K rows ksr + i*8
  const int kscb = (tid & 31) * 16;    // byte col in 512B row
  const int kkey = ksr << 4;
  const int vsr = tid >> 3;            // Vt rows vsr + i*32
  const int vscb = (tid & 7) * 16;     // byte col in 128B row
  const int vkey = (vsr & 7) << 4;
  const int rkey = (l15 & 7) << 4;     // read-side key

  const int ntiles = qt + 1;

  bf16x8 kreg[8], vreg[8];
#pragma unroll
  for (int i = 0; i < 8; ++i)
    kreg[i] = *(const bf16x8*)(kbase + (size_t)(ksr + i * 8) * 512 + kscb);
#pragma unroll
  for (int i = 0; i < 8; ++i)
    vreg[i] = *(const bf16x8*)(vtbase + (size_t)(vsr + i * 32) * 2048 + vscb);

  for (int tt = 0; tt < ntiles; ++tt) {
    const int kv0 = tt * 64;
    __syncthreads();
#pragma unroll
    for (int i = 0; i < 8; ++i)
      *(bf16x8*)((char*)Ks + (size_t)(ksr + i * 8) * 512 + (kscb ^ kkey)) = kreg[i];
#pragma unroll
    for (int i = 0; i < 8; ++i)
      *(bf16x8*)((char*)Vt + (size_t)(vsr + i * 32) * 128 + (vscb ^ vkey)) = vreg[i];
    __syncthreads();
    if (tt + 1 < ntiles) {
      const char* kp = kbase + (size_t)(kv0 + 64) * 512;
      const char* vp = vtbase + (size_t)(kv0 + 64) * 2;
#pragma unroll
      for (int i = 0; i < 8; ++i)
        kreg[i] = *(const bf16x8*)(kp + (size_t)(ksr + i * 8) * 512 + kscb);
#pragma unroll
      for (int i = 0; i < 8; ++i)
        vreg[i] = *(const bf16x8*)(vp + (size_t)(vsr + i * 32) * 2048 + vscb);
    }

    // S^T = K Q^T : col = l15 = q, rows = s (swizzled Ks reads)
    f32x4 st[4] = {};
    __builtin_amdgcn_s_setprio(1);
#pragma unroll
    for (int nf = 0; nf < 4; ++nf) {
      const char* rp = (const char*)Ks + (size_t)(nf * 16 + l15) * 512;
#pragma unroll
      for (int dc = 0; dc < 8; ++dc) {
        bf16x8 kb = *(const bf16x8*)(rp + ((dc * 64 + lg * 16) ^ rkey));
        st[nf] = MFMA16(kb, qf[dc], st[nf]);
      }
    }
    __builtin_amdgcn_s_setprio(0);

    const int qg = q0 + l15;
    float tmax = -1e30f;
#pragma unroll
    for (int nf = 0; nf < 4; ++nf)
#pragma unroll
      for (int r = 0; r < 4; ++r) {
        int sg = kv0 + nf * 16 + lg * 4 + r;
        float v = st[nf][r] * 0.0625f;
        v = (sg > qg) ? -1e30f : v;
        st[nf][r] = v;
        tmax = fmaxf(tmax, v);
      }
    tmax = fmaxf(tmax, __shfl_xor(tmax, 16, 64));
    tmax = fmaxf(tmax, __shfl_xor(tmax, 32, 64));

    if (!__all(tmax <= m_st + 8.f)) {
      float mnew = fmaxf(m_st, tmax);
      float corr = __expf(m_st - mnew);
      m_st = mnew;
      l_st *= corr;
#pragma unroll
      for (int df = 0; df < 16; ++df)
#pragma unroll
        for (int r = 0; r < 4; ++r) o[df][r] *= corr;
    }

    // P = exp(S - m), row sum, pack bf16, write P[q][s] (swizzled per-wave)
    char* psw = (char*)Ps + wid * 2048 + l15 * 128;
    float rsum = 0.f;
#pragma unroll
    for (int nf = 0; nf < 4; ++nf) {
      bf16x4 pk;
#pragma unroll
      for (int r = 0; r < 4; ++r) {
        float p = __expf(st[nf][r] - m_st);
        rsum += p;
        pk[r] = (bf16)p;
      }
      *(bf16x4*)(psw + ((nf * 32 + lg * 8) ^ rkey)) = pk;
    }
    rsum += __shfl_xor(rsum, 16, 64);
    rsum += __shfl_xor(rsum, 32, 64);
    l_st += rsum;

    // PV swapped: A = V^T rows (M=d in regs), B = P rows (N=q on lanes)
    bf16x8 pa0 = *(const bf16x8*)(psw + ((lg * 16) ^ rkey));
    bf16x8 pa1 = *(const bf16x8*)(psw + ((64 + lg * 16) ^ rkey));
    __builtin_amdgcn_s_setprio(1);
#pragma unroll
    for (int df = 0; df < 16; ++df) {
      const char* rp = (const char*)Vt + (size_t)(df * 16 + l15) * 128;
      bf16x8 vb0 = *(const bf16x8*)(rp + ((lg * 16) ^ rkey));
      bf16x8 vb1 = *(const bf16x8*)(rp + ((64 + lg * 16) ^ rkey));
      o[df] = MFMA16(vb0, pa0, o[df]);
      o[df] = MFMA16(vb1, pa1, o[df]);
    }
    __builtin_amdgcn_s_setprio(0);
  }

  // epilogue: all lane-local; vector stores along d
  float inv = 1.f / l_st;
  bf16* yp = y + (size_t)(b * 1024 + q0 + l15) * 256 + lg * 4;
#pragma unroll
  for (int df = 0; df < 16; ++df) {
    bf16x4 pk;
#pragma unroll
    for (int r = 0; r < 4; ++r) pk[r] = (bf16)(o[df][r] * inv);
    *(bf16x4*)(yp + df * 16) = pk;
  }
}

// ---------------- proj GEMM + bias + GELU (tanh form) ----------------
// v13: 256x128 tile, 512 threads / 8 waves -> 512 blocks (2 slots/CU).
// 2-barrier BK=32 step, T14 prefetch, swapped MFMA, tanh GELU.
__global__ __launch_bounds__(512) void gemm_proj(
    const bf16* __restrict__ y, const bf16* __restrict__ WT,
    const float* __restrict__ b_proj, float* __restrict__ out) {
  __shared__ __attribute__((aligned(16))) bf16 As[256][40];
  __shared__ __attribute__((aligned(16))) bf16 Bs[128][40];
  const int tid = threadIdx.x;
  // 512 blocks: xcd owns 64 = 16 M-panels x 4 N-blocks (N fastest)
  const int id = blockIdx.x;
  const int xcd = id & 7;
  const int rest = id >> 3;          // 0..63
  const int bmL = rest >> 2;         // 0..15
  const int bn = (rest & 3) * 128;
  const int bm = (xcd * 16 + bmL) * 256;
  const int lane = tid & 63, wid = tid >> 6;
  const int l15 = lane & 15, lg = lane >> 4;
  const int wm = (wid >> 1) * 64;    // 0..192
  const int wn = (wid & 1) * 64;     // 0,64
  f32x4 acc[4][4] = {};

  const int sra = tid >> 1, sca = (tid & 1) * 16;
  const int srb = tid >> 2, scb = (tid & 3) * 8;
  const bf16* yp = y + (size_t)(bm + sra) * 256 + sca;
  const bf16* wp = WT + (size_t)(bn + srb) * 256 + scb;

  // T14 prologue
  bf16x8 ha[2], hb;
  ha[0] = *(const bf16x8*)(yp);
  ha[1] = *(const bf16x8*)(yp + 8);
  hb = *(const bf16x8*)(wp);

  for (int kt = 0; kt < 8; ++kt) {
    __syncthreads();
    *(bf16x8*)&As[sra][sca] = ha[0];
    *(bf16x8*)&As[sra][sca + 8] = ha[1];
    *(bf16x8*)&Bs[srb][scb] = hb;
    __syncthreads();
    if (kt < 7) {
      ha[0] = *(const bf16x8*)(yp + (kt + 1) * 32);
      ha[1] = *(const bf16x8*)(yp + (kt + 1) * 32 + 8);
      hb = *(const bf16x8*)(wp + (kt + 1) * 32);
    }
    bf16x8 af[4], bfr[4];
#pragma unroll
    for (int mi = 0; mi < 4; ++mi)
      af[mi] = *(const bf16x8*)&As[wm + mi * 16 + l15][lg * 8];
#pragma unroll
    for (int ni = 0; ni < 4; ++ni)
      bfr[ni] = *(const bf16x8*)&Bs[wn + ni * 16 + l15][lg * 8];
    // swapped: A = W (N side in regs), B = y (M side on lanes)
    __builtin_amdgcn_s_setprio(1);
#pragma unroll
    for (int mi = 0; mi < 4; ++mi)
#pragma unroll
      for (int ni = 0; ni < 4; ++ni)
        acc[mi][ni] = MFMA16(bfr[ni], af[mi], acc[mi][ni]);
    __builtin_amdgcn_s_setprio(0);
  }

  // epilogue: row = bm+wm+mi*16+l15, cols = bn+wn+ni*16+lg*4 + r
#pragma unroll
  for (int ni = 0; ni < 4; ++ni) {
    int gc0 = bn + wn + ni * 16 + lg * 4;
    f32x4 bias = *(const f32x4*)(b_proj + gc0);
#pragma unroll
    for (int mi = 0; mi < 4; ++mi) {
      int gr = bm + wm + mi * 16 + l15;
      f32x4 g;
#pragma unroll
      for (int r = 0; r < 4; ++r) {
        float v = acc[mi][ni][r] + bias[r];
        float z = 1.5957691216f * (v + 0.044715f * v * v * v);
        float t = __expf(z);
        float th = 1.f - 2.f / (t + 1.f);   // tanh, overflow-safe
        g[r] = 0.5f * v * (1.f + th);
      }
      *(f32x4*)(out + (size_t)gr * 512 + gc0) = g;
    }
  }
}

extern "C" void kernel_launch(void* const* d_in, const int* in_sizes, int n_in,
                              void* d_out, int out_size, void* d_ws, size_t ws_size,
                              hipStream_t stream) {
  const float* x      = (const float*)d_in[0];
  const float* W_attn = (const float*)d_in[1];
  const float* b_attn = (const float*)d_in[2];
  const float* W_proj = (const float*)d_in[3];
  const float* b_proj = (const float*)d_in[4];
  float* out = (float*)d_out;
  char* ws = (char*)d_ws;

  const size_t SZ = 16777216;  // one [32,1024,256] bf16 buffer
  bf16* WT1 = (bf16*)(ws);                       // 768*512*2 = 786432
  bf16* WT2 = (bf16*)(ws + 786432);              // 512*256*2 = 262144
  bf16* qb  = (bf16*)(ws + 1048576);
  bf16* kb  = (bf16*)(ws + 1048576 + SZ);
  bf16* vtb = (bf16*)(ws + 1048576 + 2 * SZ);    // v written transposed by qkv
  bf16* yb  = (bf16*)(ws + 1048576 + 3 * SZ);

  cvt_wattn<<<dim3(1536), dim3(256), 0, stream>>>(W_attn, WT1);
  cvt_wproj<<<dim3(512), dim3(256), 0, stream>>>(W_proj, WT2);
  gemm_qkv<<<dim3(768), dim3(512), 0, stream>>>(x, WT1, b_attn, qb, kb, vtb);
  attn_fwd<<<dim3(512), dim3(256), 0, stream>>>(qb, kb, vtb, yb);
  gemm_proj<<<dim3(512), dim3(512), 0, stream>>>(yb, WT2, b_proj, out);
}

// Round 14
// 139.985 us; speedup vs baseline: 1.0128x; 1.0128x over previous
//
#include <hip/hip_runtime.h>
#include <hip/hip_bf16.h>
#include <math.h>

typedef __bf16 bf16;
typedef __attribute__((ext_vector_type(8))) __bf16 bf16x8;
typedef __attribute__((ext_vector_type(4))) __bf16 bf16x4;
typedef __attribute__((ext_vector_type(4))) float f32x4;

#define MFMA16(a, b, c) __builtin_amdgcn_mfma_f32_16x16x32_bf16((a), (b), (c), 0, 0, 0)

// Problem dims
// B=32, T=1024, VOCAB=512, RANK=256
// x [32768, 512] f32 ; W_attn [512,768] ; b_attn[768] ; W_proj [256,512] ; b_proj[512]

// ---------------- merged weight convert+transpose ----------------
// 2048 blocks: ids 0..1535 handle W_attn (393216 elems), 1536..2047 W_proj
// (131072 elems) -- split is block-aligned, no divergent block.
__global__ __launch_bounds__(256) void cvt_w(const float* __restrict__ wa,
                                             const float* __restrict__ wp,
                                             bf16* __restrict__ wt1,
                                             bf16* __restrict__ wt2) {
  int o = blockIdx.x * 256 + threadIdx.x;
  if (o < 393216) {
    int n = o >> 9, kk = o & 511;
    wt1[o] = (bf16)wa[kk * 768 + n];          // WT1[n][k] = W_attn[k][n]
  } else {
    int o2 = o - 393216;
    int n = o2 >> 8, kk = o2 & 255;
    wt2[o2] = (bf16)wp[kk * 512 + n];         // WT2[n][k] = W_proj[k][n]
  }
}

// ---------------- qkv GEMM: [32768,512]f32 x [768,512]^T ----------------
// v14: r10 structure (BK=32, 2-barrier, swapped MFMA, fused transposed-v)
// + PREFETCH DEPTH 2: two staging reg-sets, loop unrolled x2, so each
// global load has two full K-steps to drain before its LDS-write waits.
#define QKV_LOAD(HA, HB, KT) do {                                   \
    const float* xq_ = xp + (KT) * 32;                              \
    const bf16* wq_ = wp + (KT) * 32;                               \
    f32x4 f0_ = *(const f32x4*)(xq_);                               \
    f32x4 f1_ = *(const f32x4*)(xq_ + 4);                           \
    f32x4 f2_ = *(const f32x4*)(xq_ + 8);                           \
    f32x4 f3_ = *(const f32x4*)(xq_ + 12);                          \
    for (int e_ = 0; e_ < 4; ++e_) {                                \
      HA[0][e_] = (bf16)f0_[e_]; HA[0][e_ + 4] = (bf16)f1_[e_];     \
      HA[1][e_] = (bf16)f2_[e_]; HA[1][e_ + 4] = (bf16)f3_[e_];     \
    }                                                               \
    HB[0] = *(const bf16x8*)(wq_);                                  \
    HB[1] = *(const bf16x8*)(wq_ + 8);                              \
  } while (0)

#define QKV_STEP(HA, HB, NKT, DOLOAD) do {                          \
    __syncthreads();                                                \
    *(bf16x8*)&As[srow][scol] = HA[0];                              \
    *(bf16x8*)&As[srow][scol + 8] = HA[1];                          \
    *(bf16x8*)&Bs[srow][scol] = HB[0];                              \
    *(bf16x8*)&Bs[srow][scol + 8] = HB[1];                          \
    __syncthreads();                                                \
    if (DOLOAD) QKV_LOAD(HA, HB, NKT);                              \
    bf16x8 af_[4], bf_[4];                                          \
    for (int mi_ = 0; mi_ < 4; ++mi_)                               \
      af_[mi_] = *(const bf16x8*)&As[wm + mi_ * 16 + l15][lg * 8];  \
    for (int ni_ = 0; ni_ < 4; ++ni_)                               \
      bf_[ni_] = *(const bf16x8*)&Bs[wn + ni_ * 16 + l15][lg * 8];  \
    __builtin_amdgcn_s_setprio(1);                                  \
    for (int mi_ = 0; mi_ < 4; ++mi_)                               \
      for (int ni_ = 0; ni_ < 4; ++ni_)                             \
        acc[mi_][ni_] = MFMA16(bf_[ni_], af_[mi_], acc[mi_][ni_]);  \
    __builtin_amdgcn_s_setprio(0);                                  \
  } while (0)

__global__ __launch_bounds__(256) void gemm_qkv(
    const float* __restrict__ x, const bf16* __restrict__ WT,
    const float* __restrict__ b_attn,
    bf16* __restrict__ qo, bf16* __restrict__ ko, bf16* __restrict__ vto) {
  __shared__ __attribute__((aligned(16))) bf16 As[128][40];
  __shared__ __attribute__((aligned(16))) bf16 Bs[128][40];
  const int tid = threadIdx.x;
  // 1536 blocks: xcd = id&7 owns 192 = 32 M-panels x 6 N-blocks (N fastest)
  const int id = blockIdx.x;
  const int xcd = id & 7;
  const int rest = id >> 3;          // 0..191
  const int bmL = rest / 6;          // 0..31
  const int bn = (rest % 6) * 128;
  const int bm = (xcd * 32 + bmL) * 128;
  const int lane = tid & 63, wid = tid >> 6;
  const int l15 = lane & 15, lg = lane >> 4;
  const int wm = (wid >> 1) * 64, wn = (wid & 1) * 64;

  f32x4 acc[4][4] = {};

  const int srow = tid >> 1;
  const int scol = (tid & 1) * 16;
  const float* xp = x + (size_t)(bm + srow) * 512 + scol;
  const bf16* wp = WT + (size_t)(bn + srow) * 512 + scol;

  // PF2 prologue: two staging sets, steps 0 and 1
  bf16x8 ha0[2], hb0[2], ha1[2], hb1[2];
  QKV_LOAD(ha0, hb0, 0);
  QKV_LOAD(ha1, hb1, 1);

  for (int t = 0; t < 8; ++t) {
    QKV_STEP(ha0, hb0, 2 * t + 2, t < 7);   // even step 2t
    QKV_STEP(ha1, hb1, 2 * t + 3, t < 7);   // odd step 2t+1
  }

  // epilogue: row = bm+wm+mi*16+l15 (lane), cols = bn+wn+ni*16+lg*4+r (regs)
  // seg 0=q 1=k -> row-major [t][d]; 2=v -> transposed store to vt[b][d][t]
#pragma unroll
  for (int ni = 0; ni < 4; ++ni) {
    int gc0 = bn + wn + ni * 16 + lg * 4;
    f32x4 bias = *(const f32x4*)(b_attn + gc0);
    int seg = gc0 >> 8;
    int cc = gc0 & 255;
    if (seg == 2) {
#pragma unroll
      for (int mi = 0; mi < 4; ++mi) {
        int gr = bm + wm + mi * 16 + l15;
        bf16* vp = vto + (size_t)(gr >> 10) * 262144 + (size_t)cc * 1024 + (gr & 1023);
#pragma unroll
        for (int r = 0; r < 4; ++r)
          vp[(size_t)r * 1024] = (bf16)(acc[mi][ni][r] + bias[r]);
      }
    } else {
      bf16* op = (seg == 0) ? qo : ko;
#pragma unroll
      for (int mi = 0; mi < 4; ++mi) {
        int gr = bm + wm + mi * 16 + l15;
        bf16x4 pk;
#pragma unroll
        for (int r = 0; r < 4; ++r) pk[r] = (bf16)(acc[mi][ni][r] + bias[r]);
        *(bf16x4*)(op + (size_t)gr * 256 + cc) = pk;
      }
    }
  }
}

// ---------------- flash attention, causal, scale 1/16 (r10, keep) ----------------
__global__ __launch_bounds__(256) void attn_fwd(
    const bf16* __restrict__ q, const bf16* __restrict__ k,
    const bf16* __restrict__ vt, bf16* __restrict__ y) {
  __shared__ __attribute__((aligned(16))) bf16 Ks[64 * 256];    // 32KB, 512B rows, swz
  __shared__ __attribute__((aligned(16))) bf16 Vt[256 * 64];    // 32KB, 128B rows, swz
  __shared__ __attribute__((aligned(16))) bf16 Ps[4 * 16 * 64]; // 8KB per-wave P, swz
  const int tid = threadIdx.x, lane = tid & 63, wid = tid >> 6;
  const int l15 = lane & 15, lg = lane >> 4;

  // 512 blocks: id = xcd + 8*u, u = bg + 4*j (j=0..15); batch = xcd + 8*bg
  const int id = blockIdx.x;
  const int xcd = id & 7, u = id >> 3;
  const int bg = u & 3, j = u >> 2;
  const int b = xcd + 8 * bg;
  const int qt = (j < 8) ? j : 23 - j;   // u and u+32 -> qt and 15-qt
  const int q0 = qt * 64 + wid * 16;

  bf16x8 qf[8];
  {
    const bf16* qp = q + (size_t)(b * 1024 + q0 + l15) * 256 + lg * 8;
#pragma unroll
    for (int d = 0; d < 8; ++d) qf[d] = *(const bf16x8*)(qp + d * 32);
  }
  f32x4 o[16] = {};     // o[df][r]: d = df*16 + lg*4 + r, q = q0 + l15
  float m_st = -1e30f;  // running max for q = q0+l15
  float l_st = 0.f;     // running denom

  const char* kbase = (const char*)(k + (size_t)b * 262144);
  const char* vtbase = (const char*)(vt + (size_t)b * 262144);
  const int ksr = tid >> 5;            // K rows ksr + i*8
  const int kscb = (tid & 31) * 16;    // byte col in 512B row
  const int kkey = ksr << 4;
  const int vsr = tid >> 3;            // Vt rows vsr + i*32
  const int vscb = (tid & 7) * 16;     // byte col in 128B row
  const int vkey = (vsr & 7) << 4;
  const int rkey = (l15 & 7) << 4;     // read-side key

  const int ntiles = qt + 1;

  bf16x8 kreg[8], vreg[8];
#pragma unroll
  for (int i = 0; i < 8; ++i)
    kreg[i] = *(const bf16x8*)(kbase + (size_t)(ksr + i * 8) * 512 + kscb);
#pragma unroll
  for (int i = 0; i < 8; ++i)
    vreg[i] = *(const bf16x8*)(vtbase + (size_t)(vsr + i * 32) * 2048 + vscb);

  for (int tt = 0; tt < ntiles; ++tt) {
    const int kv0 = tt * 64;
    __syncthreads();
#pragma unroll
    for (int i = 0; i < 8; ++i)
      *(bf16x8*)((char*)Ks + (size_t)(ksr + i * 8) * 512 + (kscb ^ kkey)) = kreg[i];
#pragma unroll
    for (int i = 0; i < 8; ++i)
      *(bf16x8*)((char*)Vt + (size_t)(vsr + i * 32) * 128 + (vscb ^ vkey)) = vreg[i];
    __syncthreads();
    if (tt + 1 < ntiles) {
      const char* kp = kbase + (size_t)(kv0 + 64) * 512;
      const char* vp = vtbase + (size_t)(kv0 + 64) * 2;
#pragma unroll
      for (int i = 0; i < 8; ++i)
        kreg[i] = *(const bf16x8*)(kp + (size_t)(ksr + i * 8) * 512 + kscb);
#pragma unroll
      for (int i = 0; i < 8; ++i)
        vreg[i] = *(const bf16x8*)(vp + (size_t)(vsr + i * 32) * 2048 + vscb);
    }

    // S^T = K Q^T : col = l15 = q, rows = s (swizzled Ks reads)
    f32x4 st[4] = {};
    __builtin_amdgcn_s_setprio(1);
#pragma unroll
    for (int nf = 0; nf < 4; ++nf) {
      const char* rp = (const char*)Ks + (size_t)(nf * 16 + l15) * 512;
#pragma unroll
      for (int dc = 0; dc < 8; ++dc) {
        bf16x8 kb = *(const bf16x8*)(rp + ((dc * 64 + lg * 16) ^ rkey));
        st[nf] = MFMA16(kb, qf[dc], st[nf]);
      }
    }
    __builtin_amdgcn_s_setprio(0);

    const int qg = q0 + l15;
    float tmax = -1e30f;
#pragma unroll
    for (int nf = 0; nf < 4; ++nf)
#pragma unroll
      for (int r = 0; r < 4; ++r) {
        int sg = kv0 + nf * 16 + lg * 4 + r;
        float v = st[nf][r] * 0.0625f;
        v = (sg > qg) ? -1e30f : v;
        st[nf][r] = v;
        tmax = fmaxf(tmax, v);
      }
    tmax = fmaxf(tmax, __shfl_xor(tmax, 16, 64));
    tmax = fmaxf(tmax, __shfl_xor(tmax, 32, 64));

    if (!__all(tmax <= m_st + 8.f)) {
      float mnew = fmaxf(m_st, tmax);
      float corr = __expf(m_st - mnew);
      m_st = mnew;
      l_st *= corr;
#pragma unroll
      for (int df = 0; df < 16; ++df)
#pragma unroll
        for (int r = 0; r < 4; ++r) o[df][r] *= corr;
    }

    // P = exp(S - m), row sum, pack bf16, write P[q][s] (swizzled per-wave)
    char* psw = (char*)Ps + wid * 2048 + l15 * 128;
    float rsum = 0.f;
#pragma unroll
    for (int nf = 0; nf < 4; ++nf) {
      bf16x4 pk;
#pragma unroll
      for (int r = 0; r < 4; ++r) {
        float p = __expf(st[nf][r] - m_st);
        rsum += p;
        pk[r] = (bf16)p;
      }
      *(bf16x4*)(psw + ((nf * 32 + lg * 8) ^ rkey)) = pk;
    }
    rsum += __shfl_xor(rsum, 16, 64);
    rsum += __shfl_xor(rsum, 32, 64);
    l_st += rsum;

    // PV swapped: A = V^T rows (M=d in regs), B = P rows (N=q on lanes)
    bf16x8 pa0 = *(const bf16x8*)(psw + ((lg * 16) ^ rkey));
    bf16x8 pa1 = *(const bf16x8*)(psw + ((64 + lg * 16) ^ rkey));
    __builtin_amdgcn_s_setprio(1);
#pragma unroll
    for (int df = 0; df < 16; ++df) {
      const char* rp = (const char*)Vt + (size_t)(df * 16 + l15) * 128;
      bf16x8 vb0 = *(const bf16x8*)(rp + ((lg * 16) ^ rkey));
      bf16x8 vb1 = *(const bf16x8*)(rp + ((64 + lg * 16) ^ rkey));
      o[df] = MFMA16(vb0, pa0, o[df]);
      o[df] = MFMA16(vb1, pa1, o[df]);
    }
    __builtin_amdgcn_s_setprio(0);
  }

  // epilogue: all lane-local; vector stores along d
  float inv = 1.f / l_st;
  bf16* yp = y + (size_t)(b * 1024 + q0 + l15) * 256 + lg * 4;
#pragma unroll
  for (int df = 0; df < 16; ++df) {
    bf16x4 pk;
#pragma unroll
    for (int r = 0; r < 4; ++r) pk[r] = (bf16)(o[df][r] * inv);
    *(bf16x4*)(yp + df * 16) = pk;
  }
}

// ---------------- proj GEMM + bias + GELU (tanh form) (r10, keep) ----------------
__global__ __launch_bounds__(256) void gemm_proj(
    const bf16* __restrict__ y, const bf16* __restrict__ WT,
    const float* __restrict__ b_proj, float* __restrict__ out) {
  __shared__ __attribute__((aligned(16))) bf16 As[128][40];
  __shared__ __attribute__((aligned(16))) bf16 Bs[128][40];
  const int tid = threadIdx.x;
  const int id = blockIdx.x;
  const int xcd = id & 7;
  const int rest = id >> 3;          // 0..127
  const int bmL = rest >> 2;         // 0..31
  const int bn = (rest & 3) * 128;
  const int bm = (xcd * 32 + bmL) * 128;
  const int lane = tid & 63, wid = tid >> 6;
  const int l15 = lane & 15, lg = lane >> 4;
  const int wm = (wid >> 1) * 64, wn = (wid & 1) * 64;
  f32x4 acc[4][4] = {};

  const int srow = tid >> 1, scol = (tid & 1) * 16;
  const bf16* yp = y + (size_t)(bm + srow) * 256 + scol;
  const bf16* wp = WT + (size_t)(bn + srow) * 256 + scol;

  bf16x8 ha[2], hb[2];
  ha[0] = *(const bf16x8*)(yp);
  ha[1] = *(const bf16x8*)(yp + 8);
  hb[0] = *(const bf16x8*)(wp);
  hb[1] = *(const bf16x8*)(wp + 8);

  for (int kt = 0; kt < 8; ++kt) {
    __syncthreads();
    *(bf16x8*)&As[srow][scol] = ha[0];  *(bf16x8*)&As[srow][scol + 8] = ha[1];
    *(bf16x8*)&Bs[srow][scol] = hb[0];  *(bf16x8*)&Bs[srow][scol + 8] = hb[1];
    __syncthreads();
    if (kt < 7) {
      ha[0] = *(const bf16x8*)(yp + (kt + 1) * 32);
      ha[1] = *(const bf16x8*)(yp + (kt + 1) * 32 + 8);
      hb[0] = *(const bf16x8*)(wp + (kt + 1) * 32);
      hb[1] = *(const bf16x8*)(wp + (kt + 1) * 32 + 8);
    }
    bf16x8 af[4], bfr[4];
#pragma unroll
    for (int mi = 0; mi < 4; ++mi)
      af[mi] = *(const bf16x8*)&As[wm + mi * 16 + l15][lg * 8];
#pragma unroll
    for (int ni = 0; ni < 4; ++ni)
      bfr[ni] = *(const bf16x8*)&Bs[wn + ni * 16 + l15][lg * 8];
    __builtin_amdgcn_s_setprio(1);
#pragma unroll
    for (int mi = 0; mi < 4; ++mi)
#pragma unroll
      for (int ni = 0; ni < 4; ++ni)
        acc[mi][ni] = MFMA16(bfr[ni], af[mi], acc[mi][ni]);
    __builtin_amdgcn_s_setprio(0);
  }

  // epilogue: row = bm+wm+mi*16+l15, cols = bn+wn+ni*16+lg*4 + r
#pragma unroll
  for (int ni = 0; ni < 4; ++ni) {
    int gc0 = bn + wn + ni * 16 + lg * 4;
    f32x4 bias = *(const f32x4*)(b_proj + gc0);
#pragma unroll
    for (int mi = 0; mi < 4; ++mi) {
      int gr = bm + wm + mi * 16 + l15;
      f32x4 g;
#pragma unroll
      for (int r = 0; r < 4; ++r) {
        float v = acc[mi][ni][r] + bias[r];
        float z = 1.5957691216f * (v + 0.044715f * v * v * v);
        float t = __expf(z);
        float th = 1.f - 2.f / (t + 1.f);   // tanh, overflow-safe
        g[r] = 0.5f * v * (1.f + th);
      }
      *(f32x4*)(out + (size_t)gr * 512 + gc0) = g;
    }
  }
}

extern "C" void kernel_launch(void* const* d_in, const int* in_sizes, int n_in,
                              void* d_out, int out_size, void* d_ws, size_t ws_size,
                              hipStream_t stream) {
  const float* x      = (const float*)d_in[0];
  const float* W_attn = (const float*)d_in[1];
  const float* b_attn = (const float*)d_in[2];
  const float* W_proj = (const float*)d_in[3];
  const float* b_proj = (const float*)d_in[4];
  float* out = (float*)d_out;
  char* ws = (char*)d_ws;

  const size_t SZ = 16777216;  // one [32,1024,256] bf16 buffer
  bf16* WT1 = (bf16*)(ws);                       // 768*512*2 = 786432
  bf16* WT2 = (bf16*)(ws + 786432);              // 512*256*2 = 262144
  bf16* qb  = (bf16*)(ws + 1048576);
  bf16* kb  = (bf16*)(ws + 1048576 + SZ);
  bf16* vtb = (bf16*)(ws + 1048576 + 2 * SZ);    // v written transposed by qkv
  bf16* yb  = (bf16*)(ws + 1048576 + 3 * SZ);

  cvt_w<<<dim3(2048), dim3(256), 0, stream>>>(W_attn, W_proj, WT1, WT2);
  gemm_qkv<<<dim3(1536), dim3(256), 0, stream>>>(x, WT1, b_attn, qb, kb, vtb);
  attn_fwd<<<dim3(512), dim3(256), 0, stream>>>(qb, kb, vtb, yb);
  gemm_proj<<<dim3(1024), dim3(256), 0, stream>>>(yb, WT2, b_proj, out);
}

// Round 15
// 132.596 us; speedup vs baseline: 1.0692x; 1.0557x over previous
//
#include <hip/hip_runtime.h>
#include <hip/hip_bf16.h>
#include <math.h>

typedef __bf16 bf16;
typedef __attribute__((ext_vector_type(8))) __bf16 bf16x8;
typedef __attribute__((ext_vector_type(4))) __bf16 bf16x4;
typedef __attribute__((ext_vector_type(4))) float f32x4;

#define MFMA16(a, b, c) __builtin_amdgcn_mfma_f32_16x16x32_bf16((a), (b), (c), 0, 0, 0)

// Problem dims
// B=32, T=1024, VOCAB=512, RANK=256
// x [32768, 512] f32 ; W_attn [512,768] ; b_attn[768] ; W_proj [256,512] ; b_proj[512]

// ---------------- merged weight convert+transpose ----------------
// 2048 blocks: ids 0..1535 handle W_attn (393216 elems), 1536..2047 W_proj
// (131072 elems) -- split is block-aligned, no divergent block.
__global__ __launch_bounds__(256) void cvt_w(const float* __restrict__ wa,
                                             const float* __restrict__ wp,
                                             bf16* __restrict__ wt1,
                                             bf16* __restrict__ wt2) {
  int o = blockIdx.x * 256 + threadIdx.x;
  if (o < 393216) {
    int n = o >> 9, kk = o & 511;
    wt1[o] = (bf16)wa[kk * 768 + n];          // WT1[n][k] = W_attn[k][n]
  } else {
    int o2 = o - 393216;
    int n = o2 >> 8, kk = o2 & 255;
    wt2[o2] = (bf16)wp[kk * 512 + n];         // WT2[n][k] = W_proj[k][n]
  }
}

// ---------------- qkv GEMM: [32768,512]f32 x [768,512]^T ----------------
// r10 champion: BK=32, 2-barrier step, T14 depth-1 reg-prefetch (f32->bf16
// conversion off the barrier path), swapped MFMA (W on A side -> bf16x4
// column-vector epilogue), fused transposed-v store, XCD-chunked grid.
// VGPR 80 + 64 acc = 144/wave -> 3 waves/SIMD (the occupancy knee; every
// register-heavier variant regressed: r11 BK64, r12 dbuf, r14 PF2).
__global__ __launch_bounds__(256) void gemm_qkv(
    const float* __restrict__ x, const bf16* __restrict__ WT,
    const float* __restrict__ b_attn,
    bf16* __restrict__ qo, bf16* __restrict__ ko, bf16* __restrict__ vto) {
  __shared__ __attribute__((aligned(16))) bf16 As[128][40];
  __shared__ __attribute__((aligned(16))) bf16 Bs[128][40];
  const int tid = threadIdx.x;
  // 1536 blocks: xcd = id&7 owns 192 = 32 M-panels x 6 N-blocks (N fastest)
  const int id = blockIdx.x;
  const int xcd = id & 7;
  const int rest = id >> 3;          // 0..191
  const int bmL = rest / 6;          // 0..31
  const int bn = (rest % 6) * 128;
  const int bm = (xcd * 32 + bmL) * 128;
  const int lane = tid & 63, wid = tid >> 6;
  const int l15 = lane & 15, lg = lane >> 4;
  const int wm = (wid >> 1) * 64, wn = (wid & 1) * 64;

  f32x4 acc[4][4] = {};

  const int srow = tid >> 1;
  const int scol = (tid & 1) * 16;
  const float* xp = x + (size_t)(bm + srow) * 512 + scol;
  const bf16* wp = WT + (size_t)(bn + srow) * 512 + scol;

  // T14 prologue: load + convert K-step 0 into regs
  bf16x8 ha[2], hb[2];
  {
    f32x4 f0 = *(const f32x4*)(xp);
    f32x4 f1 = *(const f32x4*)(xp + 4);
    f32x4 f2 = *(const f32x4*)(xp + 8);
    f32x4 f3 = *(const f32x4*)(xp + 12);
#pragma unroll
    for (int e = 0; e < 4; ++e) {
      ha[0][e] = (bf16)f0[e]; ha[0][e + 4] = (bf16)f1[e];
      ha[1][e] = (bf16)f2[e]; ha[1][e + 4] = (bf16)f3[e];
    }
    hb[0] = *(const bf16x8*)(wp);
    hb[1] = *(const bf16x8*)(wp + 8);
  }

  for (int kt = 0; kt < 16; ++kt) {
    __syncthreads();   // previous step's LDS reads done
    *(bf16x8*)&As[srow][scol] = ha[0];
    *(bf16x8*)&As[srow][scol + 8] = ha[1];
    *(bf16x8*)&Bs[srow][scol] = hb[0];
    *(bf16x8*)&Bs[srow][scol + 8] = hb[1];
    __syncthreads();
    if (kt < 15) {     // prefetch next K-step; drains under the MFMAs below
      f32x4 f0 = *(const f32x4*)(xp + (kt + 1) * 32);
      f32x4 f1 = *(const f32x4*)(xp + (kt + 1) * 32 + 4);
      f32x4 f2 = *(const f32x4*)(xp + (kt + 1) * 32 + 8);
      f32x4 f3 = *(const f32x4*)(xp + (kt + 1) * 32 + 12);
#pragma unroll
      for (int e = 0; e < 4; ++e) {
        ha[0][e] = (bf16)f0[e]; ha[0][e + 4] = (bf16)f1[e];
        ha[1][e] = (bf16)f2[e]; ha[1][e + 4] = (bf16)f3[e];
      }
      hb[0] = *(const bf16x8*)(wp + (kt + 1) * 32);
      hb[1] = *(const bf16x8*)(wp + (kt + 1) * 32 + 8);
    }
    bf16x8 af[4], bfr[4];
#pragma unroll
    for (int mi = 0; mi < 4; ++mi)
      af[mi] = *(const bf16x8*)&As[wm + mi * 16 + l15][lg * 8];
#pragma unroll
    for (int ni = 0; ni < 4; ++ni)
      bfr[ni] = *(const bf16x8*)&Bs[wn + ni * 16 + l15][lg * 8];
    // swapped: A = W (N side in regs), B = x (M side on lanes)
    __builtin_amdgcn_s_setprio(1);
#pragma unroll
    for (int mi = 0; mi < 4; ++mi)
#pragma unroll
      for (int ni = 0; ni < 4; ++ni)
        acc[mi][ni] = MFMA16(bfr[ni], af[mi], acc[mi][ni]);
    __builtin_amdgcn_s_setprio(0);
  }

  // epilogue: row = bm+wm+mi*16+l15 (lane), cols = bn+wn+ni*16+lg*4+r (regs)
  // seg 0=q 1=k -> row-major [t][d]; 2=v -> transposed store to vt[b][d][t]
#pragma unroll
  for (int ni = 0; ni < 4; ++ni) {
    int gc0 = bn + wn + ni * 16 + lg * 4;
    f32x4 bias = *(const f32x4*)(b_attn + gc0);
    int seg = gc0 >> 8;
    int cc = gc0 & 255;
    if (seg == 2) {
#pragma unroll
      for (int mi = 0; mi < 4; ++mi) {
        int gr = bm + wm + mi * 16 + l15;
        bf16* vp = vto + (size_t)(gr >> 10) * 262144 + (size_t)cc * 1024 + (gr & 1023);
#pragma unroll
        for (int r = 0; r < 4; ++r)
          vp[(size_t)r * 1024] = (bf16)(acc[mi][ni][r] + bias[r]);
      }
    } else {
      bf16* op = (seg == 0) ? qo : ko;
#pragma unroll
      for (int mi = 0; mi < 4; ++mi) {
        int gr = bm + wm + mi * 16 + l15;
        bf16x4 pk;
#pragma unroll
        for (int r = 0; r < 4; ++r) pk[r] = (bf16)(acc[mi][ni][r] + bias[r]);
        *(bf16x4*)(op + (size_t)gr * 256 + cc) = pk;
      }
    }
  }
}

// ---------------- flash attention, causal, scale 1/16 (r10 champion) ----------------
// QBLK=64, 4 waves, 512 blocks -> 2 blocks/CU (72KB LDS, XOR-swizzled);
// complementary qt pairing for tail balance; swapped QK^T + swapped PV so
// softmax stats and O are lane-local (q = q0+l15); defer-max; T14 staging.
__global__ __launch_bounds__(256) void attn_fwd(
    const bf16* __restrict__ q, const bf16* __restrict__ k,
    const bf16* __restrict__ vt, bf16* __restrict__ y) {
  __shared__ __attribute__((aligned(16))) bf16 Ks[64 * 256];    // 32KB, 512B rows, swz
  __shared__ __attribute__((aligned(16))) bf16 Vt[256 * 64];    // 32KB, 128B rows, swz
  __shared__ __attribute__((aligned(16))) bf16 Ps[4 * 16 * 64]; // 8KB per-wave P, swz
  const int tid = threadIdx.x, lane = tid & 63, wid = tid >> 6;
  const int l15 = lane & 15, lg = lane >> 4;

  // 512 blocks: id = xcd + 8*u, u = bg + 4*j (j=0..15); batch = xcd + 8*bg
  const int id = blockIdx.x;
  const int xcd = id & 7, u = id >> 3;
  const int bg = u & 3, j = u >> 2;
  const int b = xcd + 8 * bg;
  const int qt = (j < 8) ? j : 23 - j;   // u and u+32 -> qt and 15-qt
  const int q0 = qt * 64 + wid * 16;

  bf16x8 qf[8];
  {
    const bf16* qp = q + (size_t)(b * 1024 + q0 + l15) * 256 + lg * 8;
#pragma unroll
    for (int d = 0; d < 8; ++d) qf[d] = *(const bf16x8*)(qp + d * 32);
  }
  f32x4 o[16] = {};     // o[df][r]: d = df*16 + lg*4 + r, q = q0 + l15
  float m_st = -1e30f;  // running max for q = q0+l15
  float l_st = 0.f;     // running denom

  const char* kbase = (const char*)(k + (size_t)b * 262144);
  const char* vtbase = (const char*)(vt + (size_t)b * 262144);
  const int ksr = tid >> 5;            // K rows ksr + i*8
  const int kscb = (tid & 31) * 16;    // byte col in 512B row
  const int kkey = ksr << 4;
  const int vsr = tid >> 3;            // Vt rows vsr + i*32
  const int vscb = (tid & 7) * 16;     // byte col in 128B row
  const int vkey = (vsr & 7) << 4;
  const int rkey = (l15 & 7) << 4;     // read-side key

  const int ntiles = qt + 1;

  bf16x8 kreg[8], vreg[8];
#pragma unroll
  for (int i = 0; i < 8; ++i)
    kreg[i] = *(const bf16x8*)(kbase + (size_t)(ksr + i * 8) * 512 + kscb);
#pragma unroll
  for (int i = 0; i < 8; ++i)
    vreg[i] = *(const bf16x8*)(vtbase + (size_t)(vsr + i * 32) * 2048 + vscb);

  for (int tt = 0; tt < ntiles; ++tt) {
    const int kv0 = tt * 64;
    __syncthreads();
#pragma unroll
    for (int i = 0; i < 8; ++i)
      *(bf16x8*)((char*)Ks + (size_t)(ksr + i * 8) * 512 + (kscb ^ kkey)) = kreg[i];
#pragma unroll
    for (int i = 0; i < 8; ++i)
      *(bf16x8*)((char*)Vt + (size_t)(vsr + i * 32) * 128 + (vscb ^ vkey)) = vreg[i];
    __syncthreads();
    if (tt + 1 < ntiles) {
      const char* kp = kbase + (size_t)(kv0 + 64) * 512;
      const char* vp = vtbase + (size_t)(kv0 + 64) * 2;
#pragma unroll
      for (int i = 0; i < 8; ++i)
        kreg[i] = *(const bf16x8*)(kp + (size_t)(ksr + i * 8) * 512 + kscb);
#pragma unroll
      for (int i = 0; i < 8; ++i)
        vreg[i] = *(const bf16x8*)(vp + (size_t)(vsr + i * 32) * 2048 + vscb);
    }

    // S^T = K Q^T : col = l15 = q, rows = s (swizzled Ks reads)
    f32x4 st[4] = {};
    __builtin_amdgcn_s_setprio(1);
#pragma unroll
    for (int nf = 0; nf < 4; ++nf) {
      const char* rp = (const char*)Ks + (size_t)(nf * 16 + l15) * 512;
#pragma unroll
      for (int dc = 0; dc < 8; ++dc) {
        bf16x8 kb = *(const bf16x8*)(rp + ((dc * 64 + lg * 16) ^ rkey));
        st[nf] = MFMA16(kb, qf[dc], st[nf]);
      }
    }
    __builtin_amdgcn_s_setprio(0);

    const int qg = q0 + l15;
    float tmax = -1e30f;
#pragma unroll
    for (int nf = 0; nf < 4; ++nf)
#pragma unroll
      for (int r = 0; r < 4; ++r) {
        int sg = kv0 + nf * 16 + lg * 4 + r;
        float v = st[nf][r] * 0.0625f;
        v = (sg > qg) ? -1e30f : v;
        st[nf][r] = v;
        tmax = fmaxf(tmax, v);
      }
    tmax = fmaxf(tmax, __shfl_xor(tmax, 16, 64));
    tmax = fmaxf(tmax, __shfl_xor(tmax, 32, 64));

    // defer-max: only rescale when the tile max grew past THR=8
    if (!__all(tmax <= m_st + 8.f)) {
      float mnew = fmaxf(m_st, tmax);
      float corr = __expf(m_st - mnew);
      m_st = mnew;
      l_st *= corr;
#pragma unroll
      for (int df = 0; df < 16; ++df)
#pragma unroll
        for (int r = 0; r < 4; ++r) o[df][r] *= corr;
    }

    // P = exp(S - m), row sum, pack bf16, write P[q][s] (swizzled per-wave)
    char* psw = (char*)Ps + wid * 2048 + l15 * 128;
    float rsum = 0.f;
#pragma unroll
    for (int nf = 0; nf < 4; ++nf) {
      bf16x4 pk;
#pragma unroll
      for (int r = 0; r < 4; ++r) {
        float p = __expf(st[nf][r] - m_st);
        rsum += p;
        pk[r] = (bf16)p;
      }
      *(bf16x4*)(psw + ((nf * 32 + lg * 8) ^ rkey)) = pk;
    }
    rsum += __shfl_xor(rsum, 16, 64);
    rsum += __shfl_xor(rsum, 32, 64);
    l_st += rsum;

    // PV swapped: A = V^T rows (M=d in regs), B = P rows (N=q on lanes)
    bf16x8 pa0 = *(const bf16x8*)(psw + ((lg * 16) ^ rkey));
    bf16x8 pa1 = *(const bf16x8*)(psw + ((64 + lg * 16) ^ rkey));
    __builtin_amdgcn_s_setprio(1);
#pragma unroll
    for (int df = 0; df < 16; ++df) {
      const char* rp = (const char*)Vt + (size_t)(df * 16 + l15) * 128;
      bf16x8 vb0 = *(const bf16x8*)(rp + ((lg * 16) ^ rkey));
      bf16x8 vb1 = *(const bf16x8*)(rp + ((64 + lg * 16) ^ rkey));
      o[df] = MFMA16(vb0, pa0, o[df]);
      o[df] = MFMA16(vb1, pa1, o[df]);
    }
    __builtin_amdgcn_s_setprio(0);
  }

  // epilogue: all lane-local; vector stores along d
  float inv = 1.f / l_st;
  bf16* yp = y + (size_t)(b * 1024 + q0 + l15) * 256 + lg * 4;
#pragma unroll
  for (int df = 0; df < 16; ++df) {
    bf16x4 pk;
#pragma unroll
    for (int r = 0; r < 4; ++r) pk[r] = (bf16)(o[df][r] * inv);
    *(bf16x4*)(yp + df * 16) = pk;
  }
}

// ---------------- proj GEMM + bias + GELU (tanh form) (r10 champion) ----------------
__global__ __launch_bounds__(256) void gemm_proj(
    const bf16* __restrict__ y, const bf16* __restrict__ WT,
    const float* __restrict__ b_proj, float* __restrict__ out) {
  __shared__ __attribute__((aligned(16))) bf16 As[128][40];
  __shared__ __attribute__((aligned(16))) bf16 Bs[128][40];
  const int tid = threadIdx.x;
  // 1024 blocks: xcd owns 128 = 32 M-panels x 4 N-blocks (N fastest)
  const int id = blockIdx.x;
  const int xcd = id & 7;
  const int rest = id >> 3;          // 0..127
  const int bmL = rest >> 2;         // 0..31
  const int bn = (rest & 3) * 128;
  const int bm = (xcd * 32 + bmL) * 128;
  const int lane = tid & 63, wid = tid >> 6;
  const int l15 = lane & 15, lg = lane >> 4;
  const int wm = (wid >> 1) * 64, wn = (wid & 1) * 64;
  f32x4 acc[4][4] = {};

  const int srow = tid >> 1, scol = (tid & 1) * 16;
  const bf16* yp = y + (size_t)(bm + srow) * 256 + scol;
  const bf16* wp = WT + (size_t)(bn + srow) * 256 + scol;

  bf16x8 ha[2], hb[2];
  ha[0] = *(const bf16x8*)(yp);
  ha[1] = *(const bf16x8*)(yp + 8);
  hb[0] = *(const bf16x8*)(wp);
  hb[1] = *(const bf16x8*)(wp + 8);

  for (int kt = 0; kt < 8; ++kt) {
    __syncthreads();
    *(bf16x8*)&As[srow][scol] = ha[0];  *(bf16x8*)&As[srow][scol + 8] = ha[1];
    *(bf16x8*)&Bs[srow][scol] = hb[0];  *(bf16x8*)&Bs[srow][scol + 8] = hb[1];
    __syncthreads();
    if (kt < 7) {
      ha[0] = *(const bf16x8*)(yp + (kt + 1) * 32);
      ha[1] = *(const bf16x8*)(yp + (kt + 1) * 32 + 8);
      hb[0] = *(const bf16x8*)(wp + (kt + 1) * 32);
      hb[1] = *(const bf16x8*)(wp + (kt + 1) * 32 + 8);
    }
    bf16x8 af[4], bfr[4];
#pragma unroll
    for (int mi = 0; mi < 4; ++mi)
      af[mi] = *(const bf16x8*)&As[wm + mi * 16 + l15][lg * 8];
#pragma unroll
    for (int ni = 0; ni < 4; ++ni)
      bfr[ni] = *(const bf16x8*)&Bs[wn + ni * 16 + l15][lg * 8];
    // swapped: A = W (N side in regs), B = y (M side on lanes)
    __builtin_amdgcn_s_setprio(1);
#pragma unroll
    for (int mi = 0; mi < 4; ++mi)
#pragma unroll
      for (int ni = 0; ni < 4; ++ni)
        acc[mi][ni] = MFMA16(bfr[ni], af[mi], acc[mi][ni]);
    __builtin_amdgcn_s_setprio(0);
  }

  // epilogue: row = bm+wm+mi*16+l15, cols = bn+wn+ni*16+lg*4 + r
#pragma unroll
  for (int ni = 0; ni < 4; ++ni) {
    int gc0 = bn + wn + ni * 16 + lg * 4;
    f32x4 bias = *(const f32x4*)(b_proj + gc0);
#pragma unroll
    for (int mi = 0; mi < 4; ++mi) {
      int gr = bm + wm + mi * 16 + l15;
      f32x4 g;
#pragma unroll
      for (int r = 0; r < 4; ++r) {
        float v = acc[mi][ni][r] + bias[r];
        float z = 1.5957691216f * (v + 0.044715f * v * v * v);
        float t = __expf(z);
        float th = 1.f - 2.f / (t + 1.f);   // tanh, overflow-safe
        g[r] = 0.5f * v * (1.f + th);
      }
      *(f32x4*)(out + (size_t)gr * 512 + gc0) = g;
    }
  }
}

extern "C" void kernel_launch(void* const* d_in, const int* in_sizes, int n_in,
                              void* d_out, int out_size, void* d_ws, size_t ws_size,
                              hipStream_t stream) {
  const float* x      = (const float*)d_in[0];
  const float* W_attn = (const float*)d_in[1];
  const float* b_attn = (const float*)d_in[2];
  const float* W_proj = (const float*)d_in[3];
  const float* b_proj = (const float*)d_in[4];
  float* out = (float*)d_out;
  char* ws = (char*)d_ws;

  const size_t SZ = 16777216;  // one [32,1024,256] bf16 buffer
  bf16* WT1 = (bf16*)(ws);                       // 768*512*2 = 786432
  bf16* WT2 = (bf16*)(ws + 786432);              // 512*256*2 = 262144
  bf16* qb  = (bf16*)(ws + 1048576);
  bf16* kb  = (bf16*)(ws + 1048576 + SZ);
  bf16* vtb = (bf16*)(ws + 1048576 + 2 * SZ);    // v written transposed by qkv
  bf16* yb  = (bf16*)(ws + 1048576 + 3 * SZ);

  cvt_w<<<dim3(2048), dim3(256), 0, stream>>>(W_attn, W_proj, WT1, WT2);
  gemm_qkv<<<dim3(1536), dim3(256), 0, stream>>>(x, WT1, b_attn, qb, kb, vtb);
  attn_fwd<<<dim3(512), dim3(256), 0, stream>>>(qb, kb, vtb, yb);
  gemm_proj<<<dim3(1024), dim3(256), 0, stream>>>(yb, WT2, b_proj, out);
}